// Round 11
// baseline (128.253 us; speedup 1.0000x reference)
//
#include <hip/hip_runtime.h>
#include <math.h>

// Problem constants: N=8, S=8192, C=1, K=1024, V=64
#define NS   65536
#define KK   1024
#define VV   64
#define SPB  256              // samples per block (16 waves, 1024 threads)
#define NB   (NS / SPB)       // 256 blocks -> exactly 1 block/CU (VGPR-capacity bound)
#define CPW  64               // codes per wave (16 waves cover all 1024)

// Output layout (flat, return order):
#define OUT0_OFF 0            // (8,8192,1,64) = 4,194,304
#define OUT1_OFF 4194304
#define OUT2_OFF 4259840
#define ENT_OFF  4325376      // entropy scalar; doubles as completion counter

// ws layout: [0,4K) hist u32; [4K,8K) cinit f32; [8K,264K) xn f32; [272K, 272K+8M) x_bf16
#define WS_CINIT 4096
#define WS_XN    8192
#define WS_XBF   278528       // 16B-aligned

typedef __attribute__((ext_vector_type(8))) short bf16x8;
typedef __attribute__((ext_vector_type(4))) float f32x4;

__device__ __forceinline__ unsigned f2bfu(float f) {   // bf16 bits (RNE), low 16
    unsigned u = __float_as_uint(f);
    return (u + 0x7fffu + ((u >> 16) & 1u)) >> 16;
}

// grid 260 x 256:
//   blocks 0..255 : convert x rows to bf16 + per-row |x|^2
//   blocks 256..259: cinit (=1-0.5|e|^2), hist zero, entCnt zero
__global__ void vq_prep(const float* __restrict__ x, const float* __restrict__ emb,
                        unsigned int* __restrict__ hist, float* __restrict__ cinit,
                        float* __restrict__ xn, unsigned int* __restrict__ xbf,
                        unsigned int* __restrict__ entCnt) {
    const int t = threadIdx.x;
    if (blockIdx.x < 256) {
        const int row = blockIdx.x * 256 + t;          // one sample row per thread
        const float4* xp = (const float4*)(x + (size_t)row * VV);
        unsigned int* op = xbf + (size_t)row * (VV / 2);
        float s = 0.f;
        #pragma unroll
        for (int i = 0; i < 16; ++i) {
            float4 f = xp[i];
            s = fmaf(f.x, f.x, s); s = fmaf(f.y, f.y, s);
            s = fmaf(f.z, f.z, s); s = fmaf(f.w, f.w, s);
            op[2 * i]     = (f2bfu(f.y) << 16) | f2bfu(f.x);
            op[2 * i + 1] = (f2bfu(f.w) << 16) | f2bfu(f.z);
        }
        xn[row] = s;
    } else {
        const int c = (blockIdx.x - 256) * 256 + t;    // one code per thread
        const float4* ep = (const float4*)(emb + (size_t)c * VV);
        float s = 0.f;
        #pragma unroll
        for (int i = 0; i < 16; ++i) {
            float4 f = ep[i];
            s = fmaf(f.x, f.x, s); s = fmaf(f.y, f.y, s);
            s = fmaf(f.z, f.z, s); s = fmaf(f.w, f.w, s);
        }
        cinit[c] = 1.0f - 0.5f * s;    // folded into MFMA C; scores stay in (0.85,1.15)
        hist[c] = 0u;
        if (c == 0) entCnt[0] = 0u;
    }
}

__global__ __launch_bounds__(1024, 1) void vq_main(
    const float* __restrict__ emb, const float* __restrict__ cinit,
    const unsigned short* __restrict__ xbf, const float* __restrict__ xn,
    unsigned int* __restrict__ hist,
    float* __restrict__ out0, float* __restrict__ out1, float* __restrict__ out2,
    float* __restrict__ entOut)
{
    __shared__ unsigned sWB[SPB * 20];   // per-(sample,wave) packed best; stride 20 (bank-spread)
    __shared__ int      sBest[SPB];
    __shared__ float    sPart[16];
    __shared__ unsigned sLast;

    const int tid  = threadIdx.x;        // 16 waves
    const int w    = tid >> 6;
    const int lane = tid & 63;
    const int col  = lane & 15;          // MFMA col: B-row (sample) / A-row m (code)
    const int quad = lane >> 4;          // k-granule group / D-row group
    const int samp0 = blockIdx.x * SPB;

    // ---- A fragments: this wave's 64 codes (4 tiles x 2 k-halves), + C-inits ----
    bf16x8 aLo[4], aHi[4];
    f32x4  ci[4];
    #pragma unroll
    for (int ct = 0; ct < 4; ++ct) {
        const int code = w * CPW + ct * 16 + col;
        const float* ep = emb + (size_t)code * VV + quad * 8;
        float4 p0 = *(const float4*)(ep);
        float4 p1 = *(const float4*)(ep + 4);
        float4 p2 = *(const float4*)(ep + 32);
        float4 p3 = *(const float4*)(ep + 36);
        bf16x8 lo, hi;
        lo[0]=(short)f2bfu(p0.x); lo[1]=(short)f2bfu(p0.y); lo[2]=(short)f2bfu(p0.z); lo[3]=(short)f2bfu(p0.w);
        lo[4]=(short)f2bfu(p1.x); lo[5]=(short)f2bfu(p1.y); lo[6]=(short)f2bfu(p1.z); lo[7]=(short)f2bfu(p1.w);
        hi[0]=(short)f2bfu(p2.x); hi[1]=(short)f2bfu(p2.y); hi[2]=(short)f2bfu(p2.z); hi[3]=(short)f2bfu(p2.w);
        hi[4]=(short)f2bfu(p3.x); hi[5]=(short)f2bfu(p3.y); hi[6]=(short)f2bfu(p3.z); hi[7]=(short)f2bfu(p3.w);
        aLo[ct] = lo; aHi[ct] = hi;
        ci[ct] = *(const f32x4*)(cinit + w * CPW + ct * 16 + quad * 4);
    }
    // packed-index constants: inv = 1023 - code, code = w*64 + ct*16 + quad*4 + r
    unsigned inv[16];
    {
        const unsigned invq = 1023u - (unsigned)(w * CPW) - (unsigned)(quad * 4);
        #pragma unroll
        for (int ct = 0; ct < 4; ++ct)
            #pragma unroll
            for (int r = 0; r < 4; ++r) inv[ct * 4 + r] = invq - (unsigned)(ct * 16 + r);
    }

    // ---- barrier-free K-loop: stream 16 x-tiles (block working set = 32 KB = L1) ----
    #pragma unroll
    for (int tl = 0; tl < 16; ++tl) {
        const unsigned short* xp = xbf + (size_t)(samp0 + tl * 16 + col) * VV + quad * 8;
        bf16x8 b0 = *(const bf16x8*)(xp);
        bf16x8 b1 = *(const bf16x8*)(xp + 32);
        unsigned best = 0u;
        #pragma unroll
        for (int ct = 0; ct < 4; ++ct) {
            f32x4 acc = __builtin_amdgcn_mfma_f32_16x16x32_bf16(aLo[ct], b0, ci[ct], 0, 0, 0);
            acc       = __builtin_amdgcn_mfma_f32_16x16x32_bf16(aHi[ct], b1, acc,    0, 0, 0);
            unsigned p0 = (__float_as_uint(acc[0]) & 0xFFFFFC00u) | inv[ct * 4 + 0];
            unsigned p1 = (__float_as_uint(acc[1]) & 0xFFFFFC00u) | inv[ct * 4 + 1];
            unsigned p2 = (__float_as_uint(acc[2]) & 0xFFFFFC00u) | inv[ct * 4 + 2];
            unsigned p3 = (__float_as_uint(acc[3]) & 0xFFFFFC00u) | inv[ct * 4 + 3];
            unsigned q0 = p0 > p1 ? p0 : p1;
            unsigned q1 = p2 > p3 ? p2 : p3;
            unsigned q2 = q0 > q1 ? q0 : q1;
            best = best > q2 ? best : q2;              // compiler folds into v_max3_u32
        }
        // reduce over the 4 quad-replicas (rows are in-lane; quads hold disjoint row-groups)
        unsigned o = (unsigned)__shfl_xor((int)best, 16, 64); best = best > o ? best : o;
        o          = (unsigned)__shfl_xor((int)best, 32, 64); best = best > o ? best : o;
        if (quad == 0) sWB[(tl * 16 + col) * 20 + w] = best;   // per-wave best for sample
    }
    __syncthreads();   // the ONLY main-loop-adjacent barrier

    // ---- cross-wave argmax (16 entries per sample), epilogue for out1/out2/hist ----
    {
        const int s = tid >> 2, e = tid & 3;
        const unsigned* p4 = &sWB[s * 20 + e * 4];
        unsigned m0 = p4[0] > p4[1] ? p4[0] : p4[1];
        unsigned m1 = p4[2] > p4[3] ? p4[2] : p4[3];
        unsigned m  = m0 > m1 ? m0 : m1;
        unsigned o  = (unsigned)__shfl_xor((int)m, 1, 64); m = m > o ? m : o;
        o           = (unsigned)__shfl_xor((int)m, 2, 64); m = m > o ? m : o;
        if (e == 0) {
            const int code = 1023 - (int)(m & 1023u);
            float sf = __uint_as_float(m & 0xFFFFFC00u);
            float d  = fmaf(-2.f, sf - 1.0f, xn[samp0 + s]);   // d^2 = |x|^2 - 2(score-1)
            out1[samp0 + s] = d;
            out2[samp0 + s] = d;
            atomicAdd(&hist[code], 1u);
            sBest[s] = code;
        }
    }
    __syncthreads();

    // ---- out0 gather-write: 64B contiguous per thread (R3-proven dense pattern) ----
    {
        const int smp = tid >> 2;
        const int v0  = (tid & 3) * 16;
        const int code = sBest[smp];
        const float4* src = (const float4*)(emb + (size_t)code * VV + v0);
        float4*       dst = (float4*)(out0 + (size_t)(samp0 + smp) * VV + v0);
        #pragma unroll
        for (int i = 0; i < 4; ++i) dst[i] = src[i];
    }

    // ---- completion counter + fused entropy in the last block ----
    __syncthreads();   // vmcnt drain => this block's hist atomics globally visible
    unsigned int* entCnt = (unsigned int*)entOut;
    if (tid == 0) sLast = (atomicAdd(entCnt, 1u) == (NB - 1)) ? 1u : 0u;
    __syncthreads();
    if (sLast) {
        unsigned c = atomicAdd(&hist[tid], 0u);        // coherent read, one bin/thread
        float e = 0.f;
        if (c) { float p = (float)c * (1.0f / (float)NS); e = -p * logf(p); }
        #pragma unroll
        for (int off = 32; off > 0; off >>= 1) e += __shfl_down(e, off, 64);
        if (lane == 0) sPart[w] = e;
        __syncthreads();
        if (w == 0) {
            float v = (lane < 16) ? sPart[lane] : 0.f;
            #pragma unroll
            for (int off = 8; off > 0; off >>= 1) v += __shfl_down(v, off, 64);
            if (lane == 0) entOut[0] = v;
        }
    }
}

extern "C" void kernel_launch(void* const* d_in, const int* in_sizes, int n_in,
                              void* d_out, int out_size, void* d_ws, size_t ws_size,
                              hipStream_t stream) {
    const float* x   = (const float*)d_in[0];   // (8,8192,1,64) fp32
    const float* emb = (const float*)d_in[1];   // (1,1024,64) fp32
    float* out = (float*)d_out;
    unsigned int*   hist  = (unsigned int*)d_ws;
    float*          cinit = (float*)((char*)d_ws + WS_CINIT);
    float*          xnv   = (float*)((char*)d_ws + WS_XN);
    unsigned int*   xbf   = (unsigned int*)((char*)d_ws + WS_XBF);

    vq_prep<<<260, 256, 0, stream>>>(x, emb, hist, cinit, xnv, xbf,
                                     (unsigned int*)(out + ENT_OFF));
    vq_main<<<NB, 1024, 0, stream>>>(emb, cinit, (const unsigned short*)xbf, xnv, hist,
                                     out + OUT0_OFF, out + OUT1_OFF, out + OUT2_OFF,
                                     out + ENT_OFF);
}